// Round 8
// baseline (182.996 us; speedup 1.0000x reference)
//
#include <hip/hip_runtime.h>
#include <math.h>

#define NEG_SLOPE 0.2f

typedef unsigned int u32;
typedef unsigned short u16;
typedef unsigned long long u64;

typedef __attribute__((ext_vector_type(8))) short short8;   // 8 bf16 = 4 VGPR (MFMA A/B frag)
typedef __attribute__((ext_vector_type(4))) float f32x4;    // MFMA C/D frag

__device__ __forceinline__ float bf2f(u16 h) {
  union { u32 u; float f; } c; c.u = ((u32)h) << 16; return c.f;
}
__device__ __forceinline__ u16 f2bf(float f) {
  union { float f; u32 u; } c; c.f = f;
  return (u16)((c.u + 0x7FFFu + ((c.u >> 16) & 1u)) >> 16);  // RNE, no NaNs expected
}

// ---------------------------------------------------------------- zero workspace (replaces slow runtime fill)
__global__ void k_zero(uint4* __restrict__ p, int n16) {
  int i = blockIdx.x * 256 + threadIdx.x;
  if (i < n16) p[i] = (uint4){0u, 0u, 0u, 0u};
}

// ---------------------------------------------------------------- degree + edge-weight sum, packed u64 atomic, 4-way sharded
__global__ void k_deg(const int* __restrict__ dst, const float* __restrict__ ew,
                      u64* __restrict__ packed, u16* __restrict__ rank, int E, int n) {
  int e = blockIdx.x * 256 + threadIdx.x;
  if (e >= E) return;
  u32 fix = __float2uint_rn(ew[e] * 1048576.0f);
  u64 old = atomicAdd(&packed[(size_t)(e & 3) * n + dst[e]], (1ULL << 32) | (u64)fix);
  rank[e] = (u16)(old >> 32);
}

// ---------------------------------------------------------------- hierarchical scan of (deg+1) -> row_ptr
__global__ __launch_bounds__(256) void k_part(const u64* __restrict__ packed,
                                              int* __restrict__ part, int n) {
  int i = blockIdx.x * 256 + threadIdx.x;
  int v = 0;
  if (i < n) {
    u64 pk = packed[i] + packed[(size_t)n + i] + packed[2 * (size_t)n + i] + packed[3 * (size_t)n + i];
    v = (int)(pk >> 32) + 1;
  }
  #pragma unroll
  for (int off = 32; off; off >>= 1) v += __shfl_xor(v, off);
  __shared__ int ws[4];
  if ((threadIdx.x & 63) == 0) ws[threadIdx.x >> 6] = v;
  __syncthreads();
  if (threadIdx.x == 0) part[blockIdx.x] = ws[0] + ws[1] + ws[2] + ws[3];
}

__global__ __launch_bounds__(256) void k_scanpart(int* __restrict__ part, int nb) {
  __shared__ int wsum[4];
  int carry = 0;
  for (int base = 0; base < nb; base += 256) {
    int idx = base + threadIdx.x;
    int orig = (idx < nb) ? part[idx] : 0;
    int v = orig;
    #pragma unroll
    for (int off = 1; off < 64; off <<= 1) {
      int u = __shfl_up(v, off);
      if ((threadIdx.x & 63) >= off) v += u;
    }
    if ((threadIdx.x & 63) == 63) wsum[threadIdx.x >> 6] = v;
    __syncthreads();
    int w = threadIdx.x >> 6;
    int add = 0;
    if (w > 0) add += wsum[0];
    if (w > 1) add += wsum[1];
    if (w > 2) add += wsum[2];
    int excl = v - orig + add + carry;
    if (idx < nb) part[idx] = excl;
    int total = wsum[0] + wsum[1] + wsum[2] + wsum[3];
    __syncthreads();
    carry += total;
  }
}

// phase 3: row_ptr + per-shard base offsets + self-loop entry (slot 0, packed u32)
__global__ __launch_bounds__(256) void k_rowptr(const u64* __restrict__ packed,
                                                const int* __restrict__ part_off,
                                                int* __restrict__ row_ptr,
                                                int4* __restrict__ base4,
                                                u32* __restrict__ col, int n) {
  int i = blockIdx.x * 256 + threadIdx.x;
  u64 q0 = 0, q1 = 0, q2 = 0, q3 = 0;
  if (i < n) {
    q0 = packed[i]; q1 = packed[(size_t)n + i];
    q2 = packed[2 * (size_t)n + i]; q3 = packed[3 * (size_t)n + i];
  }
  int c0 = (int)(q0 >> 32), c1 = (int)(q1 >> 32), c2 = (int)(q2 >> 32), c3 = (int)(q3 >> 32);
  int d = c0 + c1 + c2 + c3;
  u32 sumfix = (u32)q0 + (u32)q1 + (u32)q2 + (u32)q3;
  int orig = (i < n) ? d + 1 : 0;
  int v = orig;
  #pragma unroll
  for (int off = 1; off < 64; off <<= 1) {
    int u = __shfl_up(v, off);
    if ((threadIdx.x & 63) >= off) v += u;
  }
  __shared__ int wsum[4];
  if ((threadIdx.x & 63) == 63) wsum[threadIdx.x >> 6] = v;
  __syncthreads();
  int w = threadIdx.x >> 6;
  int add = 0;
  if (w > 0) add += wsum[0];
  if (w > 1) add += wsum[1];
  if (w > 2) add += wsum[2];
  if (i < n) {
    int excl = v - orig + add + part_off[blockIdx.x];
    row_ptr[i] = excl;
    int b = excl + 1;
    base4[i] = make_int4(b, b + c0, b + c0 + c1, b + c0 + c1 + c2);
    float mean = ((float)sumfix * (1.0f / 1048576.0f)) / (float)(d > 1 ? d : 1);
    u32 wq = (u32)(mean * 65536.0f); if (wq > 65535u) wq = 65535u;
    col[excl] = (u32)i | (wq << 16);                     // self-loop at slot 0
    if (i == n - 1) row_ptr[n] = excl + orig;
  }
}

// ---------------------------------------------------------------- place real edges into CSR slots (no atomics)
__global__ void k_scatter(const int* __restrict__ src, const int* __restrict__ dst,
                          const float* __restrict__ ew, const u16* __restrict__ rank,
                          const int* __restrict__ base4,
                          u32* __restrict__ col, int E) {
  int e = blockIdx.x * 256 + threadIdx.x;
  if (e >= E) return;
  int p = base4[4 * dst[e] + (e & 3)] + rank[e];
  u32 wq = (u32)(ew[e] * 65536.0f); if (wq > 65535u) wq = 65535u;
  col[p] = (u32)src[e] | (wq << 16);
}

// ---------------------------------------------------------------- W -> MFMA B-fragments, hi/lo split planes
template<int H>
__global__ void k_bfrag(const float* __restrict__ W, uint4* __restrict__ bfrag) {
  int tid = blockIdx.x * 256 + threadIdx.x;
  int f = tid >> 6, lane = tid & 63;
  const int NF = H * 4 * 4 * 2;
  if (f >= NF) return;
  int p = f & 1, t = (f >> 1) & 3, cg = f >> 3;
  int colc = 16 * cg + (lane & 15);
  int k0 = 32 * t + 8 * (lane >> 4);
  u16 v[8];
  #pragma unroll
  for (int j = 0; j < 8; j++) {
    float w = W[(size_t)(k0 + j) * (H * 64) + colc];
    u32 bits = __float_as_uint(w);
    if (p == 0) v[j] = (u16)(bits >> 16);
    else        v[j] = f2bf(w - __uint_as_float(bits & 0xffff0000u));
  }
  uint4 o = { (u32)v[0] | ((u32)v[1] << 16), (u32)v[2] | ((u32)v[3] << 16),
              (u32)v[4] | ((u32)v[5] << 16), (u32)v[6] | ((u32)v[7] << 16) };
  bfrag[f * 64 + lane] = o;
}

// ---------------------------------------------------------------- MFMA GEMM (K=128), hi/lo split, bf16 store + fused attn dots
template<int H>
__global__ __launch_bounds__(256) void k_gemm_mfma(const float* __restrict__ A,
                                                   const uint4* __restrict__ bfrag,
                                                   u16* __restrict__ xs_bf,
                                                   const float* __restrict__ att_src,
                                                   const float* __restrict__ att_dst,
                                                   float* __restrict__ a_src_out,
                                                   float* __restrict__ a_dst_out,
                                                   int nrows) {
  const int NCG = H * 4;
  int lane = threadIdx.x & 63;
  int wv = threadIdx.x >> 6;
  int lrow = lane & 15, lk = lane >> 4;
  int r0 = blockIdx.x * 64 + wv * 16;
  int arow = r0 + lrow; if (arow > nrows - 1) arow = nrows - 1;
  const float* ap = A + (size_t)arow * 128;

  f32x4 acc[NCG];
  #pragma unroll
  for (int cg = 0; cg < NCG; cg++) acc[cg] = (f32x4){0.f, 0.f, 0.f, 0.f};

  #pragma unroll
  for (int t = 0; t < 4; t++) {
    float4 av0 = *(const float4*)(ap + 32 * t + 8 * lk);
    float4 av1 = *(const float4*)(ap + 32 * t + 8 * lk + 4);
    float af[8] = {av0.x, av0.y, av0.z, av0.w, av1.x, av1.y, av1.z, av1.w};
    short8 ahi, alo;
    #pragma unroll
    for (int j = 0; j < 8; j++) {
      u32 bits = __float_as_uint(af[j]);
      ahi[j] = (short)(bits >> 16);
      alo[j] = (short)f2bf(af[j] - __uint_as_float(bits & 0xffff0000u));
    }
    #pragma unroll
    for (int cg = 0; cg < NCG; cg++) {
      union { uint4 u; short8 s; } bh, bl;
      bh.u = bfrag[((cg * 4 + t) * 2 + 0) * 64 + lane];
      bl.u = bfrag[((cg * 4 + t) * 2 + 1) * 64 + lane];
      acc[cg] = __builtin_amdgcn_mfma_f32_16x16x32_bf16(ahi, bh.s, acc[cg], 0, 0, 0);
      acc[cg] = __builtin_amdgcn_mfma_f32_16x16x32_bf16(ahi, bl.s, acc[cg], 0, 0, 0);
      acc[cg] = __builtin_amdgcn_mfma_f32_16x16x32_bf16(alo, bh.s, acc[cg], 0, 0, 0);
    }
  }

  float ps[2][4], pd[2][4];
  #pragma unroll
  for (int h = 0; h < 2; h++)
    #pragma unroll
    for (int r = 0; r < 4; r++) { ps[h][r] = 0.f; pd[h][r] = 0.f; }

  #pragma unroll
  for (int cg = 0; cg < NCG; cg++) {
    int colbase = 16 * cg + lrow;
    float asv = att_src[colbase];
    float adv = att_dst[colbase];
    const int h = (H == 2) ? (cg >> 2) : 0;
    #pragma unroll
    for (int r = 0; r < 4; r++) {
      ps[h][r] += acc[cg][r] * asv;
      pd[h][r] += acc[cg][r] * adv;
      int row = r0 + 4 * lk + r;
      if (row < nrows) xs_bf[(size_t)row * (H * 64) + colbase] = f2bf(acc[cg][r]);
    }
  }
  #pragma unroll
  for (int h = 0; h < H; h++)
    #pragma unroll
    for (int r = 0; r < 4; r++)
      #pragma unroll
      for (int off = 8; off; off >>= 1) {
        ps[h][r] += __shfl_xor(ps[h][r], off);
        pd[h][r] += __shfl_xor(pd[h][r], off);
      }
  if (lrow == 0) {
    #pragma unroll
    for (int r = 0; r < 4; r++) {
      int row = r0 + 4 * lk + r;
      if (row < nrows) {
        #pragma unroll
        for (int h = 0; h < H; h++) {
          a_src_out[row * H + h] = ps[h][r];
          a_dst_out[row * H + h] = pd[h][r];
        }
      }
    }
  }
}

// ---------------------------------------------------------------- edge-attention scalars
__global__ void k_scalars(const float* __restrict__ We1, const float* __restrict__ ae1,
                          const float* __restrict__ We2, const float* __restrict__ ae2,
                          float* __restrict__ out) {
  int t = threadIdx.x;
  if (t == 0) { float s = 0; for (int c = 0; c < 64; c++) s += We1[c] * ae1[c]; out[0] = s; }
  if (t == 1) { float s = 0; for (int c = 0; c < 64; c++) s += We1[64 + c] * ae1[64 + c]; out[1] = s; }
  if (t == 2) { float s = 0; for (int c = 0; c < 64; c++) s += We2[c] * ae2[c]; out[2] = s; }
}

// ---------------------------------------------------------------- layer 1 agg: 16-lane group per node, batched gathers
__global__ __launch_bounds__(256) void k_agg1(const int* __restrict__ row_ptr,
                                              const u32* __restrict__ col,
                                              const float2* __restrict__ a_src,
                                              const float2* __restrict__ a_dst,
                                              const float* __restrict__ scal,
                                              const u16* __restrict__ xs_bf,
                                              const float* __restrict__ b1,
                                              float* __restrict__ h_out, int n) {
  int wid = (blockIdx.x * 256 + threadIdx.x) >> 4;
  int gl = threadIdx.x & 15;
  if (wid >= n) return;
  int beg = row_ptr[wid], end = row_ptr[wid + 1];
  float2 ad = a_dst[wid];
  float sc0 = scal[0], sc1 = scal[1];
  bool hi = gl >= 8;
  float m0 = -1e30f, m1 = -1e30f, den0 = 0.f, den1 = 0.f;
  float acc[8] = {0.f, 0.f, 0.f, 0.f, 0.f, 0.f, 0.f, 0.f};
  for (int p0 = beg; p0 < end; p0 += 16) {
    int p = p0 + gl;
    bool act = p < end;
    u32 sw = col[act ? p : beg];
    int s = (int)(sw & 0xFFFFu);
    float w = (float)(sw >> 16) * (1.0f / 65536.0f);
    float2 asv = a_src[s];
    float l0 = asv.x + ad.x + w * sc0;
    float l1 = asv.y + ad.y + w * sc1;
    l0 = l0 > 0.f ? l0 : NEG_SLOPE * l0;
    l1 = l1 > 0.f ? l1 : NEG_SLOPE * l1;
    if (!act) { l0 = -1e30f; l1 = -1e30f; }
    float cm0 = l0, cm1 = l1;
    #pragma unroll
    for (int off = 8; off; off >>= 1) {
      cm0 = fmaxf(cm0, __shfl_xor(cm0, off, 16));
      cm1 = fmaxf(cm1, __shfl_xor(cm1, off, 16));
    }
    float nm0 = fmaxf(m0, cm0), nm1 = fmaxf(m1, cm1);
    float e0 = __expf(l0 - nm0), e1 = __expf(l1 - nm1);
    float cs0 = e0, cs1 = e1;
    #pragma unroll
    for (int off = 8; off; off >>= 1) {
      cs0 += __shfl_xor(cs0, off, 16);
      cs1 += __shfl_xor(cs1, off, 16);
    }
    float r0 = __expf(m0 - nm0), r1 = __expf(m1 - nm1);
    den0 = den0 * r0 + cs0;
    den1 = den1 * r1 + cs1;
    float rs = hi ? r1 : r0;
    #pragma unroll
    for (int f = 0; f < 8; f++) acc[f] *= rs;
    m0 = nm0; m1 = nm1;
    int cnt = end - p0; if (cnt > 16) cnt = 16;
    // batched gather: 8 loads in flight, then accumulate
    for (int b0 = 0; b0 < cnt; b0 += 8) {
      int bc = cnt - b0; if (bc > 8) bc = 8;
      if (bc == 8) {
        uint4 q[8];
        #pragma unroll
        for (int j = 0; j < 8; j++) {
          int sj = __shfl(s, b0 + j, 16);
          q[j] = *(const uint4*)&xs_bf[(size_t)sj * 128 + 8 * gl];
        }
        #pragma unroll
        for (int j = 0; j < 8; j++) {
          float a0 = __shfl(e0, b0 + j, 16);
          float a1 = __shfl(e1, b0 + j, 16);
          float al = hi ? a1 : a0;
          acc[0] += al * bf2f((u16)q[j].x); acc[1] += al * bf2f((u16)(q[j].x >> 16));
          acc[2] += al * bf2f((u16)q[j].y); acc[3] += al * bf2f((u16)(q[j].y >> 16));
          acc[4] += al * bf2f((u16)q[j].z); acc[5] += al * bf2f((u16)(q[j].z >> 16));
          acc[6] += al * bf2f((u16)q[j].w); acc[7] += al * bf2f((u16)(q[j].w >> 16));
        }
      } else {
        for (int j = b0; j < cnt; j++) {
          float a0 = __shfl(e0, j, 16);
          float a1 = __shfl(e1, j, 16);
          int   sj = __shfl(s, j, 16);
          uint4 q = *(const uint4*)&xs_bf[(size_t)sj * 128 + 8 * gl];
          float al = hi ? a1 : a0;
          acc[0] += al * bf2f((u16)q.x); acc[1] += al * bf2f((u16)(q.x >> 16));
          acc[2] += al * bf2f((u16)q.y); acc[3] += al * bf2f((u16)(q.y >> 16));
          acc[4] += al * bf2f((u16)q.z); acc[5] += al * bf2f((u16)(q.z >> 16));
          acc[6] += al * bf2f((u16)q.w); acc[7] += al * bf2f((u16)(q.w >> 16));
        }
      }
    }
  }
  float inv = 1.f / ((hi ? den1 : den0) + 1e-16f);
  float4 blo = *(const float4*)&b1[8 * gl];
  float4 bhi = *(const float4*)&b1[8 * gl + 4];
  float o[8];
  o[0] = acc[0] * inv + blo.x; o[1] = acc[1] * inv + blo.y;
  o[2] = acc[2] * inv + blo.z; o[3] = acc[3] * inv + blo.w;
  o[4] = acc[4] * inv + bhi.x; o[5] = acc[5] * inv + bhi.y;
  o[6] = acc[6] * inv + bhi.z; o[7] = acc[7] * inv + bhi.w;
  #pragma unroll
  for (int f = 0; f < 8; f++) o[f] = o[f] > 0.f ? o[f] : expm1f(o[f]);   // ELU
  float* dst = &h_out[(size_t)wid * 128 + 8 * gl];
  *(float4*)dst = make_float4(o[0], o[1], o[2], o[3]);
  *(float4*)(dst + 4) = make_float4(o[4], o[5], o[6], o[7]);
}

// ---------------------------------------------------------------- layer 2 agg: 16-lane group per node, batched gathers
__global__ __launch_bounds__(256) void k_agg2(const int* __restrict__ row_ptr,
                                              const u32* __restrict__ col,
                                              const float* __restrict__ a_src,
                                              const float* __restrict__ a_dst,
                                              const float* __restrict__ scal,
                                              const u16* __restrict__ xs_bf,
                                              const float* __restrict__ b2,
                                              float* __restrict__ out, int n) {
  int wid = (blockIdx.x * 256 + threadIdx.x) >> 4;
  int gl = threadIdx.x & 15;
  if (wid >= n) return;
  int beg = row_ptr[wid], end = row_ptr[wid + 1];
  float adv = a_dst[wid];
  float sc = scal[2];
  float m = -1e30f, den = 0.f;
  float acc[4] = {0.f, 0.f, 0.f, 0.f};
  for (int p0 = beg; p0 < end; p0 += 16) {
    int p = p0 + gl;
    bool act = p < end;
    u32 sw = col[act ? p : beg];
    int s = (int)(sw & 0xFFFFu);
    float w = (float)(sw >> 16) * (1.0f / 65536.0f);
    float l = a_src[s] + adv + w * sc;
    l = l > 0.f ? l : NEG_SLOPE * l;
    if (!act) l = -1e30f;
    float cm = l;
    #pragma unroll
    for (int off = 8; off; off >>= 1) cm = fmaxf(cm, __shfl_xor(cm, off, 16));
    float nm = fmaxf(m, cm);
    float e = __expf(l - nm);
    float cs = e;
    #pragma unroll
    for (int off = 8; off; off >>= 1) cs += __shfl_xor(cs, off, 16);
    float r = __expf(m - nm);
    den = den * r + cs;
    #pragma unroll
    for (int f = 0; f < 4; f++) acc[f] *= r;
    m = nm;
    int cnt = end - p0; if (cnt > 16) cnt = 16;
    for (int b0 = 0; b0 < cnt; b0 += 8) {
      int bc = cnt - b0; if (bc > 8) bc = 8;
      if (bc == 8) {
        uint2 q[8];
        #pragma unroll
        for (int j = 0; j < 8; j++) {
          int sj = __shfl(s, b0 + j, 16);
          q[j] = *(const uint2*)&xs_bf[(size_t)sj * 64 + 4 * gl];
        }
        #pragma unroll
        for (int j = 0; j < 8; j++) {
          float aj = __shfl(e, b0 + j, 16);
          acc[0] += aj * bf2f((u16)q[j].x); acc[1] += aj * bf2f((u16)(q[j].x >> 16));
          acc[2] += aj * bf2f((u16)q[j].y); acc[3] += aj * bf2f((u16)(q[j].y >> 16));
        }
      } else {
        for (int j = b0; j < cnt; j++) {
          float aj = __shfl(e, j, 16);
          int   sj = __shfl(s, j, 16);
          uint2 q = *(const uint2*)&xs_bf[(size_t)sj * 64 + 4 * gl];
          acc[0] += aj * bf2f((u16)q.x); acc[1] += aj * bf2f((u16)(q.x >> 16));
          acc[2] += aj * bf2f((u16)q.y); acc[3] += aj * bf2f((u16)(q.y >> 16));
        }
      }
    }
  }
  float inv = 1.f / (den + 1e-16f);
  float4 b = *(const float4*)&b2[4 * gl];
  *(float4*)&out[(size_t)wid * 64 + 4 * gl] =
      make_float4(acc[0] * inv + b.x, acc[1] * inv + b.y,
                  acc[2] * inv + b.z, acc[3] * inv + b.w);
}

// ================================================================ launch
extern "C" void kernel_launch(void* const* d_in, const int* in_sizes, int n_in,
                              void* d_out, int out_size, void* d_ws, size_t ws_size,
                              hipStream_t stream) {
  const float* x   = (const float*)d_in[0];
  const int*   ei  = (const int*)d_in[1];
  const float* ew  = (const float*)d_in[2];
  const float* W1  = (const float*)d_in[3];
  const float* as1 = (const float*)d_in[4];
  const float* ad1 = (const float*)d_in[5];
  const float* We1 = (const float*)d_in[6];
  const float* ae1 = (const float*)d_in[7];
  const float* b1  = (const float*)d_in[8];
  const float* W2  = (const float*)d_in[9];
  const float* as2 = (const float*)d_in[10];
  const float* ad2 = (const float*)d_in[11];
  const float* We2 = (const float*)d_in[12];
  const float* ae2 = (const float*)d_in[13];
  const float* b2  = (const float*)d_in[14];

  const int n = in_sizes[0] / 128;
  const int E = in_sizes[1] / 2;
  const int Etot = E + n;
  const int nb = (n + 255) / 256;

  char* wsb = (char*)d_ws;
  size_t off = 0;
  auto alloc = [&](size_t bytes) -> void* {
    void* p = wsb + off; off += (bytes + 255) & ~(size_t)255; return p;
  };
  u64*   packed  = (u64*)  alloc((size_t)n * 4 * 8);   // 4 shards: deg<<32 | sum_w_fix20
  u16*   rank    = (u16*)  alloc((size_t)E * 2);
  int*   row_ptr = (int*)  alloc((size_t)(n + 1) * 4);
  int*   base4   = (int*)  alloc((size_t)n * 4 * 4);
  int*   part    = (int*)  alloc((size_t)nb * 4);
  u32*   col     = (u32*)  alloc((size_t)Etot * 4);    // src:16 | wq:16
  uint4* bfrag1  = (uint4*)alloc((size_t)64 * 64 * 16);
  uint4* bfrag2  = (uint4*)alloc((size_t)32 * 64 * 16);
  u16*   xs_bf   = (u16*)  alloc((size_t)n * 128 * 2);
  float* h1      = (float*)alloc((size_t)n * 128 * 4);
  float* a_src1v = (float*)alloc((size_t)n * 2 * 4);
  float* a_dst1v = (float*)alloc((size_t)n * 2 * 4);
  float* a_src2v = (float*)alloc((size_t)n * 4);
  float* a_dst2v = (float*)alloc((size_t)n * 4);
  float* scal    = (float*)alloc(64);
  if (off > ws_size) return;

  dim3 B(256);
  int nzero16 = n * 2;  // n*4*8 bytes / 16
  k_zero<<<dim3((nzero16 + 255) / 256), B, 0, stream>>>((uint4*)packed, nzero16);
  k_deg<<<dim3((E + 255) / 256), B, 0, stream>>>(ei + E, ew, packed, rank, E, n);
  k_bfrag<2><<<dim3(16), B, 0, stream>>>(W1, bfrag1);
  k_bfrag<1><<<dim3(8), B, 0, stream>>>(W2, bfrag2);
  k_scalars<<<1, 64, 0, stream>>>(We1, ae1, We2, ae2, scal);
  k_part<<<dim3(nb), B, 0, stream>>>(packed, part, n);
  k_scanpart<<<1, B, 0, stream>>>(part, nb);
  k_rowptr<<<dim3(nb), B, 0, stream>>>(packed, part, row_ptr, (int4*)base4, col, n);
  k_scatter<<<dim3((E + 255) / 256), B, 0, stream>>>(ei, ei + E, ew, rank, base4, col, E);
  // layer 1
  k_gemm_mfma<2><<<dim3((n + 63) / 64), B, 0, stream>>>(x, bfrag1, xs_bf, as1, ad1,
                                                        a_src1v, a_dst1v, n);
  k_agg1<<<dim3((n + 15) / 16), B, 0, stream>>>(row_ptr, col,
                                                (const float2*)a_src1v,
                                                (const float2*)a_dst1v,
                                                scal, xs_bf, b1, h1, n);
  // layer 2
  k_gemm_mfma<1><<<dim3((n + 63) / 64), B, 0, stream>>>(h1, bfrag2, xs_bf, as2, ad2,
                                                        a_src2v, a_dst2v, n);
  k_agg2<<<dim3((n + 15) / 16), B, 0, stream>>>(row_ptr, col, a_src2v, a_dst2v,
                                                scal, xs_bf, b2, (float*)d_out, n);
}

// Round 9
// 177.155 us; speedup vs baseline: 1.0330x; 1.0330x over previous
//
#include <hip/hip_runtime.h>
#include <math.h>

#define NEG_SLOPE 0.2f

typedef unsigned int u32;
typedef unsigned short u16;
typedef unsigned long long u64;

typedef __attribute__((ext_vector_type(8))) short short8;   // 8 bf16 = 4 VGPR (MFMA A/B frag)
typedef __attribute__((ext_vector_type(4))) float f32x4;    // MFMA C/D frag

__device__ __forceinline__ float bf2f(u16 h) {
  union { u32 u; float f; } c; c.u = ((u32)h) << 16; return c.f;
}
__device__ __forceinline__ u16 f2bf(float f) {
  union { float f; u32 u; } c; c.f = f;
  return (u16)((c.u + 0x7FFFu + ((c.u >> 16) & 1u)) >> 16);  // RNE, no NaNs expected
}

// ---------------------------------------------------------------- zero workspace (replaces slow runtime fill)
__global__ void k_zero(uint4* __restrict__ p, int n16) {
  int i = blockIdx.x * 256 + threadIdx.x;
  if (i < n16) p[i] = (uint4){0u, 0u, 0u, 0u};
}

// ---------------------------------------------------------------- degree + edge-weight sum, packed u64 atomic, 4-way sharded
__global__ void k_deg(const int* __restrict__ dst, const float* __restrict__ ew,
                      u64* __restrict__ packed, u16* __restrict__ rank, int E, int n) {
  int e = blockIdx.x * 256 + threadIdx.x;
  if (e >= E) return;
  u32 fix = __float2uint_rn(ew[e] * 1048576.0f);
  u64 old = atomicAdd(&packed[(size_t)(e & 3) * n + dst[e]], (1ULL << 32) | (u64)fix);
  rank[e] = (u16)(old >> 32);
}

// ---------------------------------------------------------------- hierarchical scan of (deg+1) -> row_ptr
__global__ __launch_bounds__(256) void k_part(const u64* __restrict__ packed,
                                              int* __restrict__ part, int n) {
  int i = blockIdx.x * 256 + threadIdx.x;
  int v = 0;
  if (i < n) {
    u64 pk = packed[i] + packed[(size_t)n + i] + packed[2 * (size_t)n + i] + packed[3 * (size_t)n + i];
    v = (int)(pk >> 32) + 1;
  }
  #pragma unroll
  for (int off = 32; off; off >>= 1) v += __shfl_xor(v, off);
  __shared__ int ws[4];
  if ((threadIdx.x & 63) == 0) ws[threadIdx.x >> 6] = v;
  __syncthreads();
  if (threadIdx.x == 0) part[blockIdx.x] = ws[0] + ws[1] + ws[2] + ws[3];
}

__global__ __launch_bounds__(256) void k_scanpart(int* __restrict__ part, int nb) {
  __shared__ int wsum[4];
  int carry = 0;
  for (int base = 0; base < nb; base += 256) {
    int idx = base + threadIdx.x;
    int orig = (idx < nb) ? part[idx] : 0;
    int v = orig;
    #pragma unroll
    for (int off = 1; off < 64; off <<= 1) {
      int u = __shfl_up(v, off);
      if ((threadIdx.x & 63) >= off) v += u;
    }
    if ((threadIdx.x & 63) == 63) wsum[threadIdx.x >> 6] = v;
    __syncthreads();
    int w = threadIdx.x >> 6;
    int add = 0;
    if (w > 0) add += wsum[0];
    if (w > 1) add += wsum[1];
    if (w > 2) add += wsum[2];
    int excl = v - orig + add + carry;
    if (idx < nb) part[idx] = excl;
    int total = wsum[0] + wsum[1] + wsum[2] + wsum[3];
    __syncthreads();
    carry += total;
  }
}

// phase 3: row_ptr + per-shard base offsets + self-loop entry (slot 0, packed u32)
__global__ __launch_bounds__(256) void k_rowptr(const u64* __restrict__ packed,
                                                const int* __restrict__ part_off,
                                                int* __restrict__ row_ptr,
                                                int4* __restrict__ base4,
                                                u32* __restrict__ col, int n) {
  int i = blockIdx.x * 256 + threadIdx.x;
  u64 q0 = 0, q1 = 0, q2 = 0, q3 = 0;
  if (i < n) {
    q0 = packed[i]; q1 = packed[(size_t)n + i];
    q2 = packed[2 * (size_t)n + i]; q3 = packed[3 * (size_t)n + i];
  }
  int c0 = (int)(q0 >> 32), c1 = (int)(q1 >> 32), c2 = (int)(q2 >> 32), c3 = (int)(q3 >> 32);
  int d = c0 + c1 + c2 + c3;
  u32 sumfix = (u32)q0 + (u32)q1 + (u32)q2 + (u32)q3;
  int orig = (i < n) ? d + 1 : 0;
  int v = orig;
  #pragma unroll
  for (int off = 1; off < 64; off <<= 1) {
    int u = __shfl_up(v, off);
    if ((threadIdx.x & 63) >= off) v += u;
  }
  __shared__ int wsum[4];
  if ((threadIdx.x & 63) == 63) wsum[threadIdx.x >> 6] = v;
  __syncthreads();
  int w = threadIdx.x >> 6;
  int add = 0;
  if (w > 0) add += wsum[0];
  if (w > 1) add += wsum[1];
  if (w > 2) add += wsum[2];
  if (i < n) {
    int excl = v - orig + add + part_off[blockIdx.x];
    row_ptr[i] = excl;
    int b = excl + 1;
    base4[i] = make_int4(b, b + c0, b + c0 + c1, b + c0 + c1 + c2);
    float mean = ((float)sumfix * (1.0f / 1048576.0f)) / (float)(d > 1 ? d : 1);
    u32 wq = (u32)(mean * 65536.0f); if (wq > 65535u) wq = 65535u;
    col[excl] = (u32)i | (wq << 16);                     // self-loop at slot 0
    if (i == n - 1) row_ptr[n] = excl + orig;
  }
}

// ---------------------------------------------------------------- place real edges into CSR slots (no atomics)
__global__ void k_scatter(const int* __restrict__ src, const int* __restrict__ dst,
                          const float* __restrict__ ew, const u16* __restrict__ rank,
                          const int* __restrict__ base4,
                          u32* __restrict__ col, int E) {
  int e = blockIdx.x * 256 + threadIdx.x;
  if (e >= E) return;
  int p = base4[4 * dst[e] + (e & 3)] + rank[e];
  u32 wq = (u32)(ew[e] * 65536.0f); if (wq > 65535u) wq = 65535u;
  col[p] = (u32)src[e] | (wq << 16);
}

// ---------------------------------------------------------------- W -> MFMA B-fragments, hi/lo split planes
template<int H>
__global__ void k_bfrag(const float* __restrict__ W, uint4* __restrict__ bfrag) {
  int tid = blockIdx.x * 256 + threadIdx.x;
  int f = tid >> 6, lane = tid & 63;
  const int NF = H * 4 * 4 * 2;
  if (f >= NF) return;
  int p = f & 1, t = (f >> 1) & 3, cg = f >> 3;
  int colc = 16 * cg + (lane & 15);
  int k0 = 32 * t + 8 * (lane >> 4);
  u16 v[8];
  #pragma unroll
  for (int j = 0; j < 8; j++) {
    float w = W[(size_t)(k0 + j) * (H * 64) + colc];
    u32 bits = __float_as_uint(w);
    if (p == 0) v[j] = (u16)(bits >> 16);
    else        v[j] = f2bf(w - __uint_as_float(bits & 0xffff0000u));
  }
  uint4 o = { (u32)v[0] | ((u32)v[1] << 16), (u32)v[2] | ((u32)v[3] << 16),
              (u32)v[4] | ((u32)v[5] << 16), (u32)v[6] | ((u32)v[7] << 16) };
  bfrag[f * 64 + lane] = o;
}

// ---------------------------------------------------------------- MFMA GEMM (K=128), hi/lo split, bf16 store + fused attn dots
template<int H>
__global__ __launch_bounds__(256) void k_gemm_mfma(const float* __restrict__ A,
                                                   const uint4* __restrict__ bfrag,
                                                   u16* __restrict__ xs_bf,
                                                   const float* __restrict__ att_src,
                                                   const float* __restrict__ att_dst,
                                                   float* __restrict__ a_src_out,
                                                   float* __restrict__ a_dst_out,
                                                   int nrows) {
  const int NCG = H * 4;
  int lane = threadIdx.x & 63;
  int wv = threadIdx.x >> 6;
  int lrow = lane & 15, lk = lane >> 4;
  int r0 = blockIdx.x * 64 + wv * 16;
  int arow = r0 + lrow; if (arow > nrows - 1) arow = nrows - 1;
  const float* ap = A + (size_t)arow * 128;

  f32x4 acc[NCG];
  #pragma unroll
  for (int cg = 0; cg < NCG; cg++) acc[cg] = (f32x4){0.f, 0.f, 0.f, 0.f};

  #pragma unroll
  for (int t = 0; t < 4; t++) {
    float4 av0 = *(const float4*)(ap + 32 * t + 8 * lk);
    float4 av1 = *(const float4*)(ap + 32 * t + 8 * lk + 4);
    float af[8] = {av0.x, av0.y, av0.z, av0.w, av1.x, av1.y, av1.z, av1.w};
    short8 ahi, alo;
    #pragma unroll
    for (int j = 0; j < 8; j++) {
      u32 bits = __float_as_uint(af[j]);
      ahi[j] = (short)(bits >> 16);
      alo[j] = (short)f2bf(af[j] - __uint_as_float(bits & 0xffff0000u));
    }
    #pragma unroll
    for (int cg = 0; cg < NCG; cg++) {
      union { uint4 u; short8 s; } bh, bl;
      bh.u = bfrag[((cg * 4 + t) * 2 + 0) * 64 + lane];
      bl.u = bfrag[((cg * 4 + t) * 2 + 1) * 64 + lane];
      acc[cg] = __builtin_amdgcn_mfma_f32_16x16x32_bf16(ahi, bh.s, acc[cg], 0, 0, 0);
      acc[cg] = __builtin_amdgcn_mfma_f32_16x16x32_bf16(ahi, bl.s, acc[cg], 0, 0, 0);
      acc[cg] = __builtin_amdgcn_mfma_f32_16x16x32_bf16(alo, bh.s, acc[cg], 0, 0, 0);
    }
  }

  float ps[2][4], pd[2][4];
  #pragma unroll
  for (int h = 0; h < 2; h++)
    #pragma unroll
    for (int r = 0; r < 4; r++) { ps[h][r] = 0.f; pd[h][r] = 0.f; }

  #pragma unroll
  for (int cg = 0; cg < NCG; cg++) {
    int colbase = 16 * cg + lrow;
    float asv = att_src[colbase];
    float adv = att_dst[colbase];
    const int h = (H == 2) ? (cg >> 2) : 0;
    #pragma unroll
    for (int r = 0; r < 4; r++) {
      ps[h][r] += acc[cg][r] * asv;
      pd[h][r] += acc[cg][r] * adv;
      int row = r0 + 4 * lk + r;
      if (row < nrows) xs_bf[(size_t)row * (H * 64) + colbase] = f2bf(acc[cg][r]);
    }
  }
  #pragma unroll
  for (int h = 0; h < H; h++)
    #pragma unroll
    for (int r = 0; r < 4; r++)
      #pragma unroll
      for (int off = 8; off; off >>= 1) {
        ps[h][r] += __shfl_xor(ps[h][r], off);
        pd[h][r] += __shfl_xor(pd[h][r], off);
      }
  if (lrow == 0) {
    #pragma unroll
    for (int r = 0; r < 4; r++) {
      int row = r0 + 4 * lk + r;
      if (row < nrows) {
        #pragma unroll
        for (int h = 0; h < H; h++) {
          a_src_out[row * H + h] = ps[h][r];
          a_dst_out[row * H + h] = pd[h][r];
        }
      }
    }
  }
}

// ---------------------------------------------------------------- edge-attention scalars
__global__ void k_scalars(const float* __restrict__ We1, const float* __restrict__ ae1,
                          const float* __restrict__ We2, const float* __restrict__ ae2,
                          float* __restrict__ out) {
  int t = threadIdx.x;
  if (t == 0) { float s = 0; for (int c = 0; c < 64; c++) s += We1[c] * ae1[c]; out[0] = s; }
  if (t == 1) { float s = 0; for (int c = 0; c < 64; c++) s += We1[64 + c] * ae1[64 + c]; out[1] = s; }
  if (t == 2) { float s = 0; for (int c = 0; c < 64; c++) s += We2[c] * ae2[c]; out[2] = s; }
}

// ---------------------------------------------------------------- layer 1 agg: 16-lane group per node (4 nodes/wave)
__global__ __launch_bounds__(256) void k_agg1(const int* __restrict__ row_ptr,
                                              const u32* __restrict__ col,
                                              const float2* __restrict__ a_src,
                                              const float2* __restrict__ a_dst,
                                              const float* __restrict__ scal,
                                              const u16* __restrict__ xs_bf,
                                              const float* __restrict__ b1,
                                              float* __restrict__ h_out, int n) {
  int wid = (blockIdx.x * 256 + threadIdx.x) >> 4;
  int gl = threadIdx.x & 15;
  if (wid >= n) return;
  int beg = row_ptr[wid], end = row_ptr[wid + 1];
  float2 ad = a_dst[wid];
  float sc0 = scal[0], sc1 = scal[1];
  bool hi = gl >= 8;
  float m0 = -1e30f, m1 = -1e30f, den0 = 0.f, den1 = 0.f;
  float acc[8] = {0.f, 0.f, 0.f, 0.f, 0.f, 0.f, 0.f, 0.f};
  for (int p0 = beg; p0 < end; p0 += 16) {
    int p = p0 + gl;
    bool act = p < end;
    u32 sw = col[act ? p : beg];
    int s = (int)(sw & 0xFFFFu);
    float w = (float)(sw >> 16) * (1.0f / 65536.0f);
    float2 asv = a_src[s];
    float l0 = asv.x + ad.x + w * sc0;
    float l1 = asv.y + ad.y + w * sc1;
    l0 = l0 > 0.f ? l0 : NEG_SLOPE * l0;
    l1 = l1 > 0.f ? l1 : NEG_SLOPE * l1;
    if (!act) { l0 = -1e30f; l1 = -1e30f; }
    float cm0 = l0, cm1 = l1;
    #pragma unroll
    for (int off = 8; off; off >>= 1) {
      cm0 = fmaxf(cm0, __shfl_xor(cm0, off, 16));
      cm1 = fmaxf(cm1, __shfl_xor(cm1, off, 16));
    }
    float nm0 = fmaxf(m0, cm0), nm1 = fmaxf(m1, cm1);
    float e0 = __expf(l0 - nm0), e1 = __expf(l1 - nm1);
    float cs0 = e0, cs1 = e1;
    #pragma unroll
    for (int off = 8; off; off >>= 1) {
      cs0 += __shfl_xor(cs0, off, 16);
      cs1 += __shfl_xor(cs1, off, 16);
    }
    float r0 = __expf(m0 - nm0), r1 = __expf(m1 - nm1);
    den0 = den0 * r0 + cs0;
    den1 = den1 * r1 + cs1;
    float rs = hi ? r1 : r0;
    #pragma unroll
    for (int f = 0; f < 8; f++) acc[f] *= rs;
    m0 = nm0; m1 = nm1;
    int cnt = end - p0; if (cnt > 16) cnt = 16;
    for (int j = 0; j < cnt; j++) {
      float a0 = __shfl(e0, j, 16);
      float a1 = __shfl(e1, j, 16);
      int   sj = __shfl(s, j, 16);
      uint4 q = *(const uint4*)&xs_bf[(size_t)sj * 128 + 8 * gl];
      float al = hi ? a1 : a0;
      acc[0] += al * bf2f((u16)q.x); acc[1] += al * bf2f((u16)(q.x >> 16));
      acc[2] += al * bf2f((u16)q.y); acc[3] += al * bf2f((u16)(q.y >> 16));
      acc[4] += al * bf2f((u16)q.z); acc[5] += al * bf2f((u16)(q.z >> 16));
      acc[6] += al * bf2f((u16)q.w); acc[7] += al * bf2f((u16)(q.w >> 16));
    }
  }
  float inv = 1.f / ((hi ? den1 : den0) + 1e-16f);
  float4 blo = *(const float4*)&b1[8 * gl];
  float4 bhi = *(const float4*)&b1[8 * gl + 4];
  float o[8];
  o[0] = acc[0] * inv + blo.x; o[1] = acc[1] * inv + blo.y;
  o[2] = acc[2] * inv + blo.z; o[3] = acc[3] * inv + blo.w;
  o[4] = acc[4] * inv + bhi.x; o[5] = acc[5] * inv + bhi.y;
  o[6] = acc[6] * inv + bhi.z; o[7] = acc[7] * inv + bhi.w;
  #pragma unroll
  for (int f = 0; f < 8; f++) o[f] = o[f] > 0.f ? o[f] : expm1f(o[f]);   // ELU
  float* dst = &h_out[(size_t)wid * 128 + 8 * gl];
  *(float4*)dst = make_float4(o[0], o[1], o[2], o[3]);
  *(float4*)(dst + 4) = make_float4(o[4], o[5], o[6], o[7]);
}

// ---------------------------------------------------------------- layer 2 agg: 16-lane group per node, 4 features/lane
__global__ __launch_bounds__(256) void k_agg2(const int* __restrict__ row_ptr,
                                              const u32* __restrict__ col,
                                              const float* __restrict__ a_src,
                                              const float* __restrict__ a_dst,
                                              const float* __restrict__ scal,
                                              const u16* __restrict__ xs_bf,
                                              const float* __restrict__ b2,
                                              float* __restrict__ out, int n) {
  int wid = (blockIdx.x * 256 + threadIdx.x) >> 4;
  int gl = threadIdx.x & 15;
  if (wid >= n) return;
  int beg = row_ptr[wid], end = row_ptr[wid + 1];
  float adv = a_dst[wid];
  float sc = scal[2];
  float m = -1e30f, den = 0.f;
  float acc[4] = {0.f, 0.f, 0.f, 0.f};
  for (int p0 = beg; p0 < end; p0 += 16) {
    int p = p0 + gl;
    bool act = p < end;
    u32 sw = col[act ? p : beg];
    int s = (int)(sw & 0xFFFFu);
    float w = (float)(sw >> 16) * (1.0f / 65536.0f);
    float l = a_src[s] + adv + w * sc;
    l = l > 0.f ? l : NEG_SLOPE * l;
    if (!act) l = -1e30f;
    float cm = l;
    #pragma unroll
    for (int off = 8; off; off >>= 1) cm = fmaxf(cm, __shfl_xor(cm, off, 16));
    float nm = fmaxf(m, cm);
    float e = __expf(l - nm);
    float cs = e;
    #pragma unroll
    for (int off = 8; off; off >>= 1) cs += __shfl_xor(cs, off, 16);
    float r = __expf(m - nm);
    den = den * r + cs;
    #pragma unroll
    for (int f = 0; f < 4; f++) acc[f] *= r;
    m = nm;
    int cnt = end - p0; if (cnt > 16) cnt = 16;
    for (int j = 0; j < cnt; j++) {
      float aj = __shfl(e, j, 16);
      int   sj = __shfl(s, j, 16);
      uint2 q = *(const uint2*)&xs_bf[(size_t)sj * 64 + 4 * gl];
      acc[0] += aj * bf2f((u16)q.x); acc[1] += aj * bf2f((u16)(q.x >> 16));
      acc[2] += aj * bf2f((u16)q.y); acc[3] += aj * bf2f((u16)(q.y >> 16));
    }
  }
  float inv = 1.f / (den + 1e-16f);
  float4 b = *(const float4*)&b2[4 * gl];
  *(float4*)&out[(size_t)wid * 64 + 4 * gl] =
      make_float4(acc[0] * inv + b.x, acc[1] * inv + b.y,
                  acc[2] * inv + b.z, acc[3] * inv + b.w);
}

// ================================================================ launch
extern "C" void kernel_launch(void* const* d_in, const int* in_sizes, int n_in,
                              void* d_out, int out_size, void* d_ws, size_t ws_size,
                              hipStream_t stream) {
  const float* x   = (const float*)d_in[0];
  const int*   ei  = (const int*)d_in[1];
  const float* ew  = (const float*)d_in[2];
  const float* W1  = (const float*)d_in[3];
  const float* as1 = (const float*)d_in[4];
  const float* ad1 = (const float*)d_in[5];
  const float* We1 = (const float*)d_in[6];
  const float* ae1 = (const float*)d_in[7];
  const float* b1  = (const float*)d_in[8];
  const float* W2  = (const float*)d_in[9];
  const float* as2 = (const float*)d_in[10];
  const float* ad2 = (const float*)d_in[11];
  const float* We2 = (const float*)d_in[12];
  const float* ae2 = (const float*)d_in[13];
  const float* b2  = (const float*)d_in[14];

  const int n = in_sizes[0] / 128;
  const int E = in_sizes[1] / 2;
  const int Etot = E + n;
  const int nb = (n + 255) / 256;

  char* wsb = (char*)d_ws;
  size_t off = 0;
  auto alloc = [&](size_t bytes) -> void* {
    void* p = wsb + off; off += (bytes + 255) & ~(size_t)255; return p;
  };
  u64*   packed  = (u64*)  alloc((size_t)n * 4 * 8);   // 4 shards: deg<<32 | sum_w_fix20
  u16*   rank    = (u16*)  alloc((size_t)E * 2);
  int*   row_ptr = (int*)  alloc((size_t)(n + 1) * 4);
  int*   base4   = (int*)  alloc((size_t)n * 4 * 4);
  int*   part    = (int*)  alloc((size_t)nb * 4);
  u32*   col     = (u32*)  alloc((size_t)Etot * 4);    // src:16 | wq:16
  uint4* bfrag1  = (uint4*)alloc((size_t)64 * 64 * 16);
  uint4* bfrag2  = (uint4*)alloc((size_t)32 * 64 * 16);
  u16*   xs_bf   = (u16*)  alloc((size_t)n * 128 * 2);
  float* h1      = (float*)alloc((size_t)n * 128 * 4);
  float* a_src1v = (float*)alloc((size_t)n * 2 * 4);
  float* a_dst1v = (float*)alloc((size_t)n * 2 * 4);
  float* a_src2v = (float*)alloc((size_t)n * 4);
  float* a_dst2v = (float*)alloc((size_t)n * 4);
  float* scal    = (float*)alloc(64);
  if (off > ws_size) return;

  dim3 B(256);
  int nzero16 = n * 2;  // n*4*8 bytes / 16
  k_zero<<<dim3((nzero16 + 255) / 256), B, 0, stream>>>((uint4*)packed, nzero16);
  k_deg<<<dim3((E + 255) / 256), B, 0, stream>>>(ei + E, ew, packed, rank, E, n);
  k_bfrag<2><<<dim3(16), B, 0, stream>>>(W1, bfrag1);
  k_bfrag<1><<<dim3(8), B, 0, stream>>>(W2, bfrag2);
  k_scalars<<<1, 64, 0, stream>>>(We1, ae1, We2, ae2, scal);
  k_part<<<dim3(nb), B, 0, stream>>>(packed, part, n);
  k_scanpart<<<1, B, 0, stream>>>(part, nb);
  k_rowptr<<<dim3(nb), B, 0, stream>>>(packed, part, row_ptr, (int4*)base4, col, n);
  k_scatter<<<dim3((E + 255) / 256), B, 0, stream>>>(ei, ei + E, ew, rank, base4, col, E);
  // layer 1
  k_gemm_mfma<2><<<dim3((n + 63) / 64), B, 0, stream>>>(x, bfrag1, xs_bf, as1, ad1,
                                                        a_src1v, a_dst1v, n);
  k_agg1<<<dim3((n + 15) / 16), B, 0, stream>>>(row_ptr, col,
                                                (const float2*)a_src1v,
                                                (const float2*)a_dst1v,
                                                scal, xs_bf, b1, h1, n);
  // layer 2
  k_gemm_mfma<1><<<dim3((n + 63) / 64), B, 0, stream>>>(h1, bfrag2, xs_bf, as2, ad2,
                                                        a_src2v, a_dst2v, n);
  k_agg2<<<dim3((n + 15) / 16), B, 0, stream>>>(row_ptr, col, a_src2v, a_dst2v,
                                                scal, xs_bf, b2, (float*)d_out, n);
}

// Round 10
// 159.485 us; speedup vs baseline: 1.1474x; 1.1108x over previous
//
#include <hip/hip_runtime.h>
#include <math.h>

#define NEG_SLOPE 0.2f

typedef unsigned int u32;
typedef unsigned short u16;
typedef unsigned long long u64;

typedef __attribute__((ext_vector_type(8))) short short8;   // 8 bf16 = 4 VGPR (MFMA A/B frag)
typedef __attribute__((ext_vector_type(4))) float f32x4;    // MFMA C/D frag

__device__ __forceinline__ float bf2f(u16 h) {
  union { u32 u; float f; } c; c.u = ((u32)h) << 16; return c.f;
}
__device__ __forceinline__ u16 f2bf(float f) {
  union { float f; u32 u; } c; c.f = f;
  return (u16)((c.u + 0x7FFFu + ((c.u >> 16) & 1u)) >> 16);  // RNE, no NaNs expected
}

// ---------------------------------------------------------------- zero packed counters
__global__ void k_zero(uint4* __restrict__ p, int n16) {
  int i = blockIdx.x * 256 + threadIdx.x;
  if (i < n16) p[i] = (uint4){0u, 0u, 0u, 0u};
}

// ---------------------------------------------------------------- fused degree/weight-sum + direct CSR slot write
// packed[d] += (1<<32)|round(w*2^20); returned old>>32 = rank -> col[d*64+rank] = src|wq<<16
__global__ void k_deg(const int* __restrict__ src, const int* __restrict__ dst,
                      const float* __restrict__ ew,
                      u64* __restrict__ packed, u32* __restrict__ col, int E) {
  int e = blockIdx.x * 256 + threadIdx.x;
  if (e >= E) return;
  float w = ew[e];
  u32 fix = __float2uint_rn(w * 1048576.0f);
  int d = dst[e];
  u64 old = atomicAdd(&packed[d], (1ULL << 32) | (u64)fix);
  u32 rank = (u32)(old >> 32);
  u32 wq = (u32)(w * 65536.0f); if (wq > 65535u) wq = 65535u;
  if (rank < 64u) col[((u32)d << 6) + rank] = (u32)src[e] | (wq << 16);
}

// ---------------------------------------------------------------- W -> MFMA B-fragments, hi/lo split planes
template<int H>
__global__ void k_bfrag(const float* __restrict__ W, uint4* __restrict__ bfrag) {
  int tid = blockIdx.x * 256 + threadIdx.x;
  int f = tid >> 6, lane = tid & 63;
  const int NF = H * 4 * 4 * 2;
  if (f >= NF) return;
  int p = f & 1, t = (f >> 1) & 3, cg = f >> 3;
  int colc = 16 * cg + (lane & 15);
  int k0 = 32 * t + 8 * (lane >> 4);
  u16 v[8];
  #pragma unroll
  for (int j = 0; j < 8; j++) {
    float w = W[(size_t)(k0 + j) * (H * 64) + colc];
    u32 bits = __float_as_uint(w);
    if (p == 0) v[j] = (u16)(bits >> 16);
    else        v[j] = f2bf(w - __uint_as_float(bits & 0xffff0000u));
  }
  uint4 o = { (u32)v[0] | ((u32)v[1] << 16), (u32)v[2] | ((u32)v[3] << 16),
              (u32)v[4] | ((u32)v[5] << 16), (u32)v[6] | ((u32)v[7] << 16) };
  bfrag[f * 64 + lane] = o;
}

// ---------------------------------------------------------------- MFMA GEMM (K=128), hi/lo split, bf16 store + fused attn dots
template<int H>
__global__ __launch_bounds__(256) void k_gemm_mfma(const float* __restrict__ A,
                                                   const uint4* __restrict__ bfrag,
                                                   u16* __restrict__ xs_bf,
                                                   const float* __restrict__ att_src,
                                                   const float* __restrict__ att_dst,
                                                   float* __restrict__ a_src_out,
                                                   float* __restrict__ a_dst_out,
                                                   int nrows) {
  const int NCG = H * 4;
  int lane = threadIdx.x & 63;
  int wv = threadIdx.x >> 6;
  int lrow = lane & 15, lk = lane >> 4;
  int r0 = blockIdx.x * 64 + wv * 16;
  int arow = r0 + lrow; if (arow > nrows - 1) arow = nrows - 1;
  const float* ap = A + (size_t)arow * 128;

  f32x4 acc[NCG];
  #pragma unroll
  for (int cg = 0; cg < NCG; cg++) acc[cg] = (f32x4){0.f, 0.f, 0.f, 0.f};

  #pragma unroll
  for (int t = 0; t < 4; t++) {
    float4 av0 = *(const float4*)(ap + 32 * t + 8 * lk);
    float4 av1 = *(const float4*)(ap + 32 * t + 8 * lk + 4);
    float af[8] = {av0.x, av0.y, av0.z, av0.w, av1.x, av1.y, av1.z, av1.w};
    short8 ahi, alo;
    #pragma unroll
    for (int j = 0; j < 8; j++) {
      u32 bits = __float_as_uint(af[j]);
      ahi[j] = (short)(bits >> 16);
      alo[j] = (short)f2bf(af[j] - __uint_as_float(bits & 0xffff0000u));
    }
    #pragma unroll
    for (int cg = 0; cg < NCG; cg++) {
      union { uint4 u; short8 s; } bh, bl;
      bh.u = bfrag[((cg * 4 + t) * 2 + 0) * 64 + lane];
      bl.u = bfrag[((cg * 4 + t) * 2 + 1) * 64 + lane];
      acc[cg] = __builtin_amdgcn_mfma_f32_16x16x32_bf16(ahi, bh.s, acc[cg], 0, 0, 0);
      acc[cg] = __builtin_amdgcn_mfma_f32_16x16x32_bf16(ahi, bl.s, acc[cg], 0, 0, 0);
      acc[cg] = __builtin_amdgcn_mfma_f32_16x16x32_bf16(alo, bh.s, acc[cg], 0, 0, 0);
    }
  }

  float ps[2][4], pd[2][4];
  #pragma unroll
  for (int h = 0; h < 2; h++)
    #pragma unroll
    for (int r = 0; r < 4; r++) { ps[h][r] = 0.f; pd[h][r] = 0.f; }

  #pragma unroll
  for (int cg = 0; cg < NCG; cg++) {
    int colbase = 16 * cg + lrow;
    float asv = att_src[colbase];
    float adv = att_dst[colbase];
    const int h = (H == 2) ? (cg >> 2) : 0;
    #pragma unroll
    for (int r = 0; r < 4; r++) {
      ps[h][r] += acc[cg][r] * asv;
      pd[h][r] += acc[cg][r] * adv;
      int row = r0 + 4 * lk + r;
      if (row < nrows) xs_bf[(size_t)row * (H * 64) + colbase] = f2bf(acc[cg][r]);
    }
  }
  #pragma unroll
  for (int h = 0; h < H; h++)
    #pragma unroll
    for (int r = 0; r < 4; r++)
      #pragma unroll
      for (int off = 8; off; off >>= 1) {
        ps[h][r] += __shfl_xor(ps[h][r], off);
        pd[h][r] += __shfl_xor(pd[h][r], off);
      }
  if (lrow == 0) {
    #pragma unroll
    for (int r = 0; r < 4; r++) {
      int row = r0 + 4 * lk + r;
      if (row < nrows) {
        #pragma unroll
        for (int h = 0; h < H; h++) {
          a_src_out[row * H + h] = ps[h][r];
          a_dst_out[row * H + h] = pd[h][r];
        }
      }
    }
  }
}

// ---------------------------------------------------------------- edge-attention scalars
__global__ void k_scalars(const float* __restrict__ We1, const float* __restrict__ ae1,
                          const float* __restrict__ We2, const float* __restrict__ ae2,
                          float* __restrict__ out) {
  int t = threadIdx.x;
  if (t == 0) { float s = 0; for (int c = 0; c < 64; c++) s += We1[c] * ae1[c]; out[0] = s; }
  if (t == 1) { float s = 0; for (int c = 0; c < 64; c++) s += We1[64 + c] * ae1[64 + c]; out[1] = s; }
  if (t == 2) { float s = 0; for (int c = 0; c < 64; c++) s += We2[c] * ae2[c]; out[2] = s; }
}

// ---------------------------------------------------------------- layer 1 agg: 16-lane group/node, inline self-loop
__global__ __launch_bounds__(256) void k_agg1(const u64* __restrict__ packed,
                                              const u32* __restrict__ col,
                                              const float2* __restrict__ a_src,
                                              const float2* __restrict__ a_dst,
                                              const float* __restrict__ scal,
                                              const u16* __restrict__ xs_bf,
                                              const float* __restrict__ b1,
                                              float* __restrict__ h_out, int n) {
  int wid = (blockIdx.x * 256 + threadIdx.x) >> 4;
  int gl = threadIdx.x & 15;
  if (wid >= n) return;
  u64 pk = packed[wid];
  int deg = (int)(pk >> 32); if (deg > 64) deg = 64;
  float mean = ((float)(u32)pk * (1.0f / 1048576.0f)) / (float)(deg > 1 ? deg : 1);
  float2 ad = a_dst[wid];
  float2 asv_s = a_src[wid];
  float sc0 = scal[0], sc1 = scal[1];
  bool hi = gl >= 8;
  // self-loop initializes the online softmax
  float l0s = asv_s.x + ad.x + mean * sc0;
  float l1s = asv_s.y + ad.y + mean * sc1;
  l0s = l0s > 0.f ? l0s : NEG_SLOPE * l0s;
  l1s = l1s > 0.f ? l1s : NEG_SLOPE * l1s;
  float m0 = l0s, m1 = l1s, den0 = 1.f, den1 = 1.f;
  float acc[8];
  {
    uint4 q = *(const uint4*)&xs_bf[(size_t)wid * 128 + 8 * gl];
    acc[0] = bf2f((u16)q.x); acc[1] = bf2f((u16)(q.x >> 16));
    acc[2] = bf2f((u16)q.y); acc[3] = bf2f((u16)(q.y >> 16));
    acc[4] = bf2f((u16)q.z); acc[5] = bf2f((u16)(q.z >> 16));
    acc[6] = bf2f((u16)q.w); acc[7] = bf2f((u16)(q.w >> 16));
  }
  const u32* cw = col + ((u32)wid << 6);
  for (int p0 = 0; p0 < deg; p0 += 16) {
    int p = p0 + gl;
    bool act = p < deg;
    u32 sw = cw[act ? p : 0];
    int s = (int)(sw & 0xFFFFu);
    float w = (float)(sw >> 16) * (1.0f / 65536.0f);
    float2 asv = a_src[s];
    float l0 = asv.x + ad.x + w * sc0;
    float l1 = asv.y + ad.y + w * sc1;
    l0 = l0 > 0.f ? l0 : NEG_SLOPE * l0;
    l1 = l1 > 0.f ? l1 : NEG_SLOPE * l1;
    if (!act) { l0 = -1e30f; l1 = -1e30f; }
    float cm0 = l0, cm1 = l1;
    #pragma unroll
    for (int off = 8; off; off >>= 1) {
      cm0 = fmaxf(cm0, __shfl_xor(cm0, off, 16));
      cm1 = fmaxf(cm1, __shfl_xor(cm1, off, 16));
    }
    float nm0 = fmaxf(m0, cm0), nm1 = fmaxf(m1, cm1);
    float e0 = __expf(l0 - nm0), e1 = __expf(l1 - nm1);
    float cs0 = e0, cs1 = e1;
    #pragma unroll
    for (int off = 8; off; off >>= 1) {
      cs0 += __shfl_xor(cs0, off, 16);
      cs1 += __shfl_xor(cs1, off, 16);
    }
    float r0 = __expf(m0 - nm0), r1 = __expf(m1 - nm1);
    den0 = den0 * r0 + cs0;
    den1 = den1 * r1 + cs1;
    float rs = hi ? r1 : r0;
    #pragma unroll
    for (int f = 0; f < 8; f++) acc[f] *= rs;
    m0 = nm0; m1 = nm1;
    int cnt = deg - p0; if (cnt > 16) cnt = 16;
    for (int j = 0; j < cnt; j++) {
      float a0 = __shfl(e0, j, 16);
      float a1 = __shfl(e1, j, 16);
      int   sj = __shfl(s, j, 16);
      uint4 q = *(const uint4*)&xs_bf[(size_t)sj * 128 + 8 * gl];
      float al = hi ? a1 : a0;
      acc[0] += al * bf2f((u16)q.x); acc[1] += al * bf2f((u16)(q.x >> 16));
      acc[2] += al * bf2f((u16)q.y); acc[3] += al * bf2f((u16)(q.y >> 16));
      acc[4] += al * bf2f((u16)q.z); acc[5] += al * bf2f((u16)(q.z >> 16));
      acc[6] += al * bf2f((u16)q.w); acc[7] += al * bf2f((u16)(q.w >> 16));
    }
  }
  float inv = 1.f / ((hi ? den1 : den0) + 1e-16f);
  float4 blo = *(const float4*)&b1[8 * gl];
  float4 bhi = *(const float4*)&b1[8 * gl + 4];
  float o[8];
  o[0] = acc[0] * inv + blo.x; o[1] = acc[1] * inv + blo.y;
  o[2] = acc[2] * inv + blo.z; o[3] = acc[3] * inv + blo.w;
  o[4] = acc[4] * inv + bhi.x; o[5] = acc[5] * inv + bhi.y;
  o[6] = acc[6] * inv + bhi.z; o[7] = acc[7] * inv + bhi.w;
  #pragma unroll
  for (int f = 0; f < 8; f++) o[f] = o[f] > 0.f ? o[f] : expm1f(o[f]);   // ELU
  float* dst = &h_out[(size_t)wid * 128 + 8 * gl];
  *(float4*)dst = make_float4(o[0], o[1], o[2], o[3]);
  *(float4*)(dst + 4) = make_float4(o[4], o[5], o[6], o[7]);
}

// ---------------------------------------------------------------- layer 2 agg: 8-lane group/node (8 nodes/wave), inline self-loop
__global__ __launch_bounds__(256) void k_agg2(const u64* __restrict__ packed,
                                              const u32* __restrict__ col,
                                              const float* __restrict__ a_src,
                                              const float* __restrict__ a_dst,
                                              const float* __restrict__ scal,
                                              const u16* __restrict__ xs_bf,
                                              const float* __restrict__ b2,
                                              float* __restrict__ out, int n) {
  int wid = (blockIdx.x * 256 + threadIdx.x) >> 3;
  int gl = threadIdx.x & 7;
  if (wid >= n) return;
  u64 pk = packed[wid];
  int deg = (int)(pk >> 32); if (deg > 64) deg = 64;
  float mean = ((float)(u32)pk * (1.0f / 1048576.0f)) / (float)(deg > 1 ? deg : 1);
  float adv = a_dst[wid];
  float sc = scal[2];
  float ls = a_src[wid] + adv + mean * sc;
  ls = ls > 0.f ? ls : NEG_SLOPE * ls;
  float m = ls, den = 1.f;
  float acc[8];
  {
    uint4 q = *(const uint4*)&xs_bf[(size_t)wid * 64 + 8 * gl];
    acc[0] = bf2f((u16)q.x); acc[1] = bf2f((u16)(q.x >> 16));
    acc[2] = bf2f((u16)q.y); acc[3] = bf2f((u16)(q.y >> 16));
    acc[4] = bf2f((u16)q.z); acc[5] = bf2f((u16)(q.z >> 16));
    acc[6] = bf2f((u16)q.w); acc[7] = bf2f((u16)(q.w >> 16));
  }
  const u32* cw = col + ((u32)wid << 6);
  for (int p0 = 0; p0 < deg; p0 += 8) {
    int p = p0 + gl;
    bool act = p < deg;
    u32 sw = cw[act ? p : 0];
    int s = (int)(sw & 0xFFFFu);
    float w = (float)(sw >> 16) * (1.0f / 65536.0f);
    float l = a_src[s] + adv + w * sc;
    l = l > 0.f ? l : NEG_SLOPE * l;
    if (!act) l = -1e30f;
    float cm = l;
    #pragma unroll
    for (int off = 4; off; off >>= 1) cm = fmaxf(cm, __shfl_xor(cm, off, 8));
    float nm = fmaxf(m, cm);
    float e = __expf(l - nm);
    float cs = e;
    #pragma unroll
    for (int off = 4; off; off >>= 1) cs += __shfl_xor(cs, off, 8);
    float r = __expf(m - nm);
    den = den * r + cs;
    #pragma unroll
    for (int f = 0; f < 8; f++) acc[f] *= r;
    m = nm;
    int cnt = deg - p0; if (cnt > 8) cnt = 8;
    for (int j = 0; j < cnt; j++) {
      float aj = __shfl(e, j, 8);
      int   sj = __shfl(s, j, 8);
      uint4 q = *(const uint4*)&xs_bf[(size_t)sj * 64 + 8 * gl];
      acc[0] += aj * bf2f((u16)q.x); acc[1] += aj * bf2f((u16)(q.x >> 16));
      acc[2] += aj * bf2f((u16)q.y); acc[3] += aj * bf2f((u16)(q.y >> 16));
      acc[4] += aj * bf2f((u16)q.z); acc[5] += aj * bf2f((u16)(q.z >> 16));
      acc[6] += aj * bf2f((u16)q.w); acc[7] += aj * bf2f((u16)(q.w >> 16));
    }
  }
  float inv = 1.f / (den + 1e-16f);
  float4 blo = *(const float4*)&b2[8 * gl];
  float4 bhi = *(const float4*)&b2[8 * gl + 4];
  float* dst = &out[(size_t)wid * 64 + 8 * gl];
  *(float4*)dst = make_float4(acc[0] * inv + blo.x, acc[1] * inv + blo.y,
                              acc[2] * inv + blo.z, acc[3] * inv + blo.w);
  *(float4*)(dst + 4) = make_float4(acc[4] * inv + bhi.x, acc[5] * inv + bhi.y,
                                    acc[6] * inv + bhi.z, acc[7] * inv + bhi.w);
}

// ================================================================ launch
extern "C" void kernel_launch(void* const* d_in, const int* in_sizes, int n_in,
                              void* d_out, int out_size, void* d_ws, size_t ws_size,
                              hipStream_t stream) {
  const float* x   = (const float*)d_in[0];
  const int*   ei  = (const int*)d_in[1];
  const float* ew  = (const float*)d_in[2];
  const float* W1  = (const float*)d_in[3];
  const float* as1 = (const float*)d_in[4];
  const float* ad1 = (const float*)d_in[5];
  const float* We1 = (const float*)d_in[6];
  const float* ae1 = (const float*)d_in[7];
  const float* b1  = (const float*)d_in[8];
  const float* W2  = (const float*)d_in[9];
  const float* as2 = (const float*)d_in[10];
  const float* ad2 = (const float*)d_in[11];
  const float* We2 = (const float*)d_in[12];
  const float* ae2 = (const float*)d_in[13];
  const float* b2  = (const float*)d_in[14];

  const int n = in_sizes[0] / 128;
  const int E = in_sizes[1] / 2;

  char* wsb = (char*)d_ws;
  size_t off = 0;
  auto alloc = [&](size_t bytes) -> void* {
    void* p = wsb + off; off += (bytes + 255) & ~(size_t)255; return p;
  };
  u64*   packed  = (u64*)  alloc((size_t)n * 8);         // deg<<32 | sum_w_fix20
  u32*   col     = (u32*)  alloc((size_t)n * 64 * 4);    // 64 slots/node: src:16|wq:16
  uint4* bfrag1  = (uint4*)alloc((size_t)64 * 64 * 16);
  uint4* bfrag2  = (uint4*)alloc((size_t)32 * 64 * 16);
  u16*   xs_bf   = (u16*)  alloc((size_t)n * 128 * 2);   // layer1; reused layer2 (n*64)
  float* h1      = (float*)alloc((size_t)n * 128 * 4);
  float* a_src1v = (float*)alloc((size_t)n * 2 * 4);
  float* a_dst1v = (float*)alloc((size_t)n * 2 * 4);
  float* a_src2v = (float*)alloc((size_t)n * 4);
  float* a_dst2v = (float*)alloc((size_t)n * 4);
  float* scal    = (float*)alloc(64);
  if (off > ws_size) return;

  dim3 B(256);
  int nzero16 = (n + 1) / 2;  // n*8 bytes / 16
  k_zero<<<dim3((nzero16 + 255) / 256), B, 0, stream>>>((uint4*)packed, nzero16);
  k_deg<<<dim3((E + 255) / 256), B, 0, stream>>>(ei, ei + E, ew, packed, col, E);
  k_bfrag<2><<<dim3(16), B, 0, stream>>>(W1, bfrag1);
  k_bfrag<1><<<dim3(8), B, 0, stream>>>(W2, bfrag2);
  k_scalars<<<1, 64, 0, stream>>>(We1, ae1, We2, ae2, scal);
  // layer 1
  k_gemm_mfma<2><<<dim3((n + 63) / 64), B, 0, stream>>>(x, bfrag1, xs_bf, as1, ad1,
                                                        a_src1v, a_dst1v, n);
  k_agg1<<<dim3((n + 15) / 16), B, 0, stream>>>(packed, col,
                                                (const float2*)a_src1v,
                                                (const float2*)a_dst1v,
                                                scal, xs_bf, b1, h1, n);
  // layer 2
  k_gemm_mfma<1><<<dim3((n + 63) / 64), B, 0, stream>>>(h1, bfrag2, xs_bf, as2, ad2,
                                                        a_src2v, a_dst2v, n);
  k_agg2<<<dim3((n + 31) / 32), B, 0, stream>>>(packed, col, a_src2v, a_dst2v,
                                                scal, xs_bf, b2, (float*)d_out, n);
}